// Round 1
// baseline (710.296 us; speedup 1.0000x reference)
//
#include <hip/hip_runtime.h>
#include <math.h>

#define NATOMS 10000
#define NEDGES 200000

// T layout per atom: [species s=0..3][60 floats]:
//   l0: ofs 0,  n=0..7,  m=0      (8)
//   l1: ofs 8,  n=0..5,  m=0..2   (18)
//   l2: ofs 26, n=0..3,  m=0..4   (20)
//   l3: ofs 46, n=0..1,  m=0..6   (14)
// W2 layout (floats): l0 @0 (4096 = (s*8+n)*128+j), l1 @4096 (3072),
//                     l2 @7168 (2048), l3 @9216 (1024); total 10240.

__global__ __launch_bounds__(256) void prep_w2_kernel(
    const float* __restrict__ emb,
    const float* __restrict__ wm0, const float* __restrict__ wm1,
    const float* __restrict__ wm2, const float* __restrict__ wm3,
    float* __restrict__ W2)
{
    int tid = blockIdx.x * 256 + threadIdx.x;
    if (tid >= 10240) return;
    const float* wm; int idx, Nl;
    if (tid < 4096)      { wm = wm0; idx = tid;        Nl = 8; }
    else if (tid < 7168) { wm = wm1; idx = tid - 4096; Nl = 6; }
    else if (tid < 9216) { wm = wm2; idx = tid - 7168; Nl = 4; }
    else                 { wm = wm3; idx = tid - 9216; Nl = 2; }
    int j  = idx & 127;
    int sn = idx >> 7;
    int n  = sn % Nl;
    int s  = sn / Nl;
    float acc = 0.0f;
    #pragma unroll
    for (int c = 0; c < 16; ++c)
        acc = fmaf(wm[(n*16 + c)*128 + j], emb[s*16 + c], acc);
    W2[tid] = acc;
}

__global__ __launch_bounds__(256) void edge_kernel(
    const float* __restrict__ pos,
    const float* __restrict__ wr0, const float* __restrict__ wr1,
    const float* __restrict__ wr2, const float* __restrict__ wr3,
    const int* __restrict__ species,
    const int* __restrict__ senders,
    const int* __restrict__ receivers,
    float* __restrict__ T)
{
    int e = blockIdx.x * 256 + threadIdx.x;
    if (e >= NEDGES) return;
    int snd = senders[e];
    int rcv = receivers[e];
    int sp  = species[snd];
    float sx = pos[snd*3], sy = pos[snd*3+1], sz = pos[snd*3+2];
    float px_ = pos[rcv*3], py_ = pos[rcv*3+1], pz_ = pos[rcv*3+2];
    float dx = px_ - sx, dy = py_ - sy, dz = pz_ - sz;
    float r = sqrtf(dx*dx + dy*dy + dz*dz + 1e-12f);
    float inv_r = 1.0f / r;
    float x = dx * inv_r, y = dy * inv_r, z = dz * inv_r;

    float xr = fminf(r * 0.2f, 1.0f);
    float pxr = 3.14159265358979323846f * xr;
    float s1, c1;
    sincosf(pxr, &s1, &c1);
    float fcut = 0.5f * (c1 + 1.0f);
    float g = fcut / (xr + 0.001f);

    // bess[n] = sin((n+1)*pi*xr)/(xr+1e-3)*fcut via Chebyshev recurrence
    float bess[8];
    {
        float sm1 = 0.0f, s0 = s1;
        float tc = 2.0f * c1;
        #pragma unroll
        for (int n = 0; n < 8; ++n) {
            bess[n] = s0 * g;
            float s2 = tc * s0 - sm1;
            sm1 = s0; s0 = s2;
        }
    }

    // R_l = bess @ w_rad_l   (w_rad_l is (8, N_MAX_l) row-major)
    float R0[8], R1[6], R2[4], R3[2];
    #pragma unroll
    for (int n = 0; n < 8; ++n) R0[n] = 0.0f;
    #pragma unroll
    for (int n = 0; n < 6; ++n) R1[n] = 0.0f;
    #pragma unroll
    for (int n = 0; n < 4; ++n) R2[n] = 0.0f;
    #pragma unroll
    for (int n = 0; n < 2; ++n) R3[n] = 0.0f;
    #pragma unroll
    for (int i = 0; i < 8; ++i) {
        float b = bess[i];
        #pragma unroll
        for (int n = 0; n < 8; ++n) R0[n] = fmaf(b, wr0[i*8 + n], R0[n]);
        #pragma unroll
        for (int n = 0; n < 6; ++n) R1[n] = fmaf(b, wr1[i*6 + n], R1[n]);
        #pragma unroll
        for (int n = 0; n < 4; ++n) R2[n] = fmaf(b, wr2[i*4 + n], R2[n]);
        #pragma unroll
        for (int n = 0; n < 2; ++n) R3[n] = fmaf(b, wr3[i*2 + n], R3[n]);
    }

    // real spherical harmonics
    float xy = x*y, yz = y*z, xz = x*z;
    float x2 = x*x, y2 = y*y, z2 = z*z;
    float sh1v[3] = {0.4886025119029199f*y, 0.4886025119029199f*z, 0.4886025119029199f*x};
    float sh2v[5] = {1.0925484305920792f*xy, 1.0925484305920792f*yz,
                     0.31539156525252005f*(3.0f*z2 - 1.0f),
                     1.0925484305920792f*xz, 0.5462742152960396f*(x2 - y2)};
    float sh3v[7] = {0.5900435899266435f*y*(3.0f*x2 - y2),
                     2.890611442640554f*xy*z,
                     0.4570457994644658f*y*(5.0f*z2 - 1.0f),
                     0.3731763325901154f*z*(5.0f*z2 - 3.0f),
                     0.4570457994644658f*x*(5.0f*z2 - 1.0f),
                     1.445305721320277f*z*(x2 - y2),
                     0.5900435899266435f*x*(x2 - 3.0f*y2)};

    float* base = T + (size_t)rcv * 240 + sp * 60;
    #pragma unroll
    for (int n = 0; n < 8; ++n)
        atomicAdd(base + n, R0[n] * 0.28209479177387814f);
    #pragma unroll
    for (int n = 0; n < 6; ++n) {
        #pragma unroll
        for (int m = 0; m < 3; ++m)
            atomicAdd(base + 8 + n*3 + m, R1[n] * sh1v[m]);
    }
    #pragma unroll
    for (int n = 0; n < 4; ++n) {
        #pragma unroll
        for (int m = 0; m < 5; ++m)
            atomicAdd(base + 26 + n*5 + m, R2[n] * sh2v[m]);
    }
    #pragma unroll
    for (int n = 0; n < 2; ++n) {
        #pragma unroll
        for (int m = 0; m < 7; ++m)
            atomicAdd(base + 46 + n*7 + m, R3[n] * sh3v[m]);
    }
}

__global__ __launch_bounds__(128) void atom_kernel(
    const float* __restrict__ T,
    const float* __restrict__ W2,
    const float* __restrict__ emb2,
    const float* __restrict__ w_out,
    const float* __restrict__ comp_weights,
    const float* __restrict__ scaling,
    const int* __restrict__ species,
    const int* __restrict__ batch_seg,
    float* __restrict__ out)
{
    const int j = threadIdx.x; // 0..127 = K_MIX channel
    __shared__ float Tl[240];
    __shared__ float red[2];

    // preload this channel's W2 column into registers (persists across atoms)
    float w2r0[32], w2r1[24], w2r2[16], w2r3[8];
    #pragma unroll
    for (int i = 0; i < 32; ++i) w2r0[i] = W2[i*128 + j];
    #pragma unroll
    for (int i = 0; i < 24; ++i) w2r1[i] = W2[4096 + i*128 + j];
    #pragma unroll
    for (int i = 0; i < 16; ++i) w2r2[i] = W2[7168 + i*128 + j];
    #pragma unroll
    for (int i = 0; i < 8;  ++i) w2r3[i] = W2[9216 + i*128 + j];
    const float wo   = w_out[j];
    const float scal = scaling[0];

    for (int atom = blockIdx.x; atom < NATOMS; atom += gridDim.x) {
        if (j < 120) {
            Tl[j]       = T[(size_t)atom*240 + j];
            Tl[j + 120] = T[(size_t)atom*240 + j + 120];
        }
        __syncthreads();

        float Bj = 0.0f;
        // l = 0 (m-count 1)
        {
            float a0 = 0.0f;
            #pragma unroll
            for (int i = 0; i < 32; ++i)
                a0 = fmaf(w2r0[i], Tl[(i >> 3)*60 + (i & 7)], a0);
            Bj += a0 * a0;
        }
        // l = 1 (m-count 3), 1/sqrt(3)
        {
            float a[3] = {0.f, 0.f, 0.f};
            #pragma unroll
            for (int i = 0; i < 24; ++i) {
                const int s = i / 6, n = i % 6;
                #pragma unroll
                for (int m = 0; m < 3; ++m)
                    a[m] = fmaf(w2r1[i], Tl[s*60 + 8 + n*3 + m], a[m]);
            }
            Bj += (a[0]*a[0] + a[1]*a[1] + a[2]*a[2]) * 0.57735026918962576f;
        }
        // l = 2 (m-count 5), 1/sqrt(5)
        {
            float a[5] = {0.f, 0.f, 0.f, 0.f, 0.f};
            #pragma unroll
            for (int i = 0; i < 16; ++i) {
                const int s = i >> 2, n = i & 3;
                #pragma unroll
                for (int m = 0; m < 5; ++m)
                    a[m] = fmaf(w2r2[i], Tl[s*60 + 26 + n*5 + m], a[m]);
            }
            float ss = a[0]*a[0] + a[1]*a[1] + a[2]*a[2] + a[3]*a[3] + a[4]*a[4];
            Bj += ss * 0.44721359549995794f;
        }
        // l = 3 (m-count 7), 1/sqrt(7)
        {
            float a[7] = {0.f, 0.f, 0.f, 0.f, 0.f, 0.f, 0.f};
            #pragma unroll
            for (int i = 0; i < 8; ++i) {
                const int s = i >> 1, n = i & 1;
                #pragma unroll
                for (int m = 0; m < 7; ++m)
                    a[m] = fmaf(w2r3[i], Tl[s*60 + 46 + n*7 + m], a[m]);
            }
            float ss = 0.0f;
            #pragma unroll
            for (int m = 0; m < 7; ++m) ss = fmaf(a[m], a[m], ss);
            Bj += ss * 0.37796447300922725f;
        }

        const int sp = species[atom];
        float B4 = Bj * Bj;
        float hidden = B4 * emb2[sp*128 + j];
        float v = hidden * wo;

        // reduce across 128 threads (two wave64)
        #pragma unroll
        for (int o = 32; o > 0; o >>= 1) v += __shfl_down(v, o, 64);
        if ((j & 63) == 0) red[j >> 6] = v;
        __syncthreads();
        if (j == 0) {
            float tot = red[0] + red[1];
            float at  = fmaf(tot, scal, comp_weights[sp]);
            atomicAdd(&out[batch_seg[atom]], at);
        }
        __syncthreads();
    }
}

extern "C" void kernel_launch(void* const* d_in, const int* in_sizes, int n_in,
                              void* d_out, int out_size, void* d_ws, size_t ws_size,
                              hipStream_t stream)
{
    // setup_inputs() dict order (w_rad/w_mix interleaved):
    const float* pos  = (const float*)d_in[0];
    const float* emb  = (const float*)d_in[1];
    const float* wr0  = (const float*)d_in[2];
    const float* wm0  = (const float*)d_in[3];
    const float* wr1  = (const float*)d_in[4];
    const float* wm1  = (const float*)d_in[5];
    const float* wr2  = (const float*)d_in[6];
    const float* wm2  = (const float*)d_in[7];
    const float* wr3  = (const float*)d_in[8];
    const float* wm3  = (const float*)d_in[9];
    const float* emb2 = (const float*)d_in[10];
    const float* wout = (const float*)d_in[11];
    const float* cw   = (const float*)d_in[12];
    const float* scal = (const float*)d_in[13];
    const int* species   = (const int*)d_in[14];
    const int* senders   = (const int*)d_in[15];
    const int* receivers = (const int*)d_in[16];
    const int* batch_seg = (const int*)d_in[17];

    float* T  = (float*)d_ws;                       // NATOMS*240 floats = 9.6 MB
    float* W2 = T + (size_t)NATOMS * 240;           // 10240 floats

    hipMemsetAsync(T, 0, (size_t)NATOMS * 240 * sizeof(float), stream);
    hipMemsetAsync(d_out, 0, (size_t)out_size * sizeof(float), stream);

    prep_w2_kernel<<<40, 256, 0, stream>>>(emb, wm0, wm1, wm2, wm3, W2);
    edge_kernel<<<(NEDGES + 255)/256, 256, 0, stream>>>(
        pos, wr0, wr1, wr2, wr3, species, senders, receivers, T);
    atom_kernel<<<1024, 128, 0, stream>>>(
        T, W2, emb2, wout, cw, scal, species, batch_seg, (float*)d_out);
}

// Round 2
// 146.457 us; speedup vs baseline: 4.8499x; 4.8499x over previous
//
#include <hip/hip_runtime.h>
#include <math.h>

#define NATOMS 10000
#define NEDGES 200000

// T layout per species (60 floats):
//   l0: ofs 0,  n=0..7,  m=0      (8)
//   l1: ofs 8,  n=0..5,  m=0..2   (18)
//   l2: ofs 26, n=0..3,  m=0..4   (20)
//   l3: ofs 46, n=0..1,  m=0..6   (14)
// W2 layout (floats): l0 @0 (4096 = (s*8+n)*128+j), l1 @4096 (3072),
//                     l2 @7168 (2048), l3 @9216 (1024); total 10240.

__global__ __launch_bounds__(256) void prep_w2_kernel(
    const float* __restrict__ emb,
    const float* __restrict__ wm0, const float* __restrict__ wm1,
    const float* __restrict__ wm2, const float* __restrict__ wm3,
    float* __restrict__ W2)
{
    int tid = blockIdx.x * 256 + threadIdx.x;
    if (tid >= 10240) return;
    const float* wm; int idx, Nl;
    if (tid < 4096)      { wm = wm0; idx = tid;        Nl = 8; }
    else if (tid < 7168) { wm = wm1; idx = tid - 4096; Nl = 6; }
    else if (tid < 9216) { wm = wm2; idx = tid - 7168; Nl = 4; }
    else                 { wm = wm3; idx = tid - 9216; Nl = 2; }
    int j  = idx & 127;
    int sn = idx >> 7;
    int n  = sn % Nl;
    int s  = sn / Nl;
    float acc = 0.0f;
    #pragma unroll
    for (int c = 0; c < 16; ++c)
        acc = fmaf(wm[(n*16 + c)*128 + j], emb[s*16 + c], acc);
    W2[tid] = acc;
}

__global__ __launch_bounds__(256) void count_kernel(
    const int* __restrict__ receivers, int* __restrict__ counts)
{
    int e = blockIdx.x * 256 + threadIdx.x;
    if (e < NEDGES) atomicAdd(&counts[receivers[e]], 1);
}

__global__ __launch_bounds__(1024) void scan_kernel(
    const int* __restrict__ counts, int* __restrict__ offsets,
    int* __restrict__ cursor)
{
    __shared__ int psum[1024];
    const int t = threadIdx.x;
    int local[10];
    int sum = 0;
    #pragma unroll
    for (int k = 0; k < 10; ++k) {
        int idx = t * 10 + k;
        int c = (idx < NATOMS) ? counts[idx] : 0;
        local[k] = sum;
        sum += c;
    }
    psum[t] = sum;
    __syncthreads();
    for (int off = 1; off < 1024; off <<= 1) {
        int v = (t >= off) ? psum[t - off] : 0;
        __syncthreads();
        psum[t] += v;
        __syncthreads();
    }
    int base = (t > 0) ? psum[t - 1] : 0;
    #pragma unroll
    for (int k = 0; k < 10; ++k) {
        int idx = t * 10 + k;
        if (idx < NATOMS) {
            offsets[idx] = base + local[k];
            cursor[idx]  = base + local[k];
        }
    }
    if (t == 0) offsets[NATOMS] = NEDGES;
}

__global__ __launch_bounds__(256) void scatter_kernel(
    const int* __restrict__ receivers, int* __restrict__ cursor,
    int* __restrict__ csr)
{
    int e = blockIdx.x * 256 + threadIdx.x;
    if (e < NEDGES) {
        int p = atomicAdd(&cursor[receivers[e]], 1);
        csr[p] = e;
    }
}

__global__ __launch_bounds__(128) void fused_atom_kernel(
    const float* __restrict__ pos,
    const float* __restrict__ wr0, const float* __restrict__ wr1,
    const float* __restrict__ wr2, const float* __restrict__ wr3,
    const int* __restrict__ species,
    const int* __restrict__ senders,
    const int* __restrict__ offsets,
    const int* __restrict__ csr,
    const float* __restrict__ W2,
    const float* __restrict__ emb2,
    const float* __restrict__ w_out,
    const float* __restrict__ comp_weights,
    const float* __restrict__ scaling,
    const int* __restrict__ batch_seg,
    float* __restrict__ out)
{
    const int atom = blockIdx.x;
    const int j = threadIdx.x;  // 0..127, also the K_MIX channel in phase 2
    __shared__ float Tl[240];
    __shared__ float red[2];
    if (j < 120) { Tl[j] = 0.0f; Tl[j + 120] = 0.0f; }
    __syncthreads();

    const int beg = offsets[atom];
    const int end = offsets[atom + 1];
    const float rx = pos[atom*3], ry = pos[atom*3+1], rz = pos[atom*3+2];

    for (int i = beg + j; i < end; i += 128) {
        const int e   = csr[i];
        const int snd = senders[e];
        const int sp  = species[snd];
        float dx = rx - pos[snd*3];
        float dy = ry - pos[snd*3+1];
        float dz = rz - pos[snd*3+2];
        float r = sqrtf(dx*dx + dy*dy + dz*dz + 1e-12f);
        float inv_r = 1.0f / r;
        float x = dx * inv_r, y = dy * inv_r, z = dz * inv_r;

        float xr = fminf(r * 0.2f, 1.0f);
        float pxr = 3.14159265358979323846f * xr;
        float s1, c1;
        sincosf(pxr, &s1, &c1);
        float fcut = 0.5f * (c1 + 1.0f);
        float g = fcut / (xr + 0.001f);

        float bess[8];
        {
            float sm1 = 0.0f, s0 = s1;
            float tc = 2.0f * c1;
            #pragma unroll
            for (int n = 0; n < 8; ++n) {
                bess[n] = s0 * g;
                float s2 = tc * s0 - sm1;
                sm1 = s0; s0 = s2;
            }
        }

        float R0[8], R1[6], R2[4], R3[2];
        #pragma unroll
        for (int n = 0; n < 8; ++n) R0[n] = 0.0f;
        #pragma unroll
        for (int n = 0; n < 6; ++n) R1[n] = 0.0f;
        #pragma unroll
        for (int n = 0; n < 4; ++n) R2[n] = 0.0f;
        #pragma unroll
        for (int n = 0; n < 2; ++n) R3[n] = 0.0f;
        #pragma unroll
        for (int i2 = 0; i2 < 8; ++i2) {
            float b = bess[i2];
            #pragma unroll
            for (int n = 0; n < 8; ++n) R0[n] = fmaf(b, wr0[i2*8 + n], R0[n]);
            #pragma unroll
            for (int n = 0; n < 6; ++n) R1[n] = fmaf(b, wr1[i2*6 + n], R1[n]);
            #pragma unroll
            for (int n = 0; n < 4; ++n) R2[n] = fmaf(b, wr2[i2*4 + n], R2[n]);
            #pragma unroll
            for (int n = 0; n < 2; ++n) R3[n] = fmaf(b, wr3[i2*2 + n], R3[n]);
        }

        float xy = x*y, yz = y*z, xz = x*z;
        float x2 = x*x, y2 = y*y, z2 = z*z;
        float sh1v[3] = {0.4886025119029199f*y, 0.4886025119029199f*z, 0.4886025119029199f*x};
        float sh2v[5] = {1.0925484305920792f*xy, 1.0925484305920792f*yz,
                         0.31539156525252005f*(3.0f*z2 - 1.0f),
                         1.0925484305920792f*xz, 0.5462742152960396f*(x2 - y2)};
        float sh3v[7] = {0.5900435899266435f*y*(3.0f*x2 - y2),
                         2.890611442640554f*xy*z,
                         0.4570457994644658f*y*(5.0f*z2 - 1.0f),
                         0.3731763325901154f*z*(5.0f*z2 - 3.0f),
                         0.4570457994644658f*x*(5.0f*z2 - 1.0f),
                         1.445305721320277f*z*(x2 - y2),
                         0.5900435899266435f*x*(x2 - 3.0f*y2)};

        float* base = Tl + sp * 60;
        #pragma unroll
        for (int n = 0; n < 8; ++n)
            atomicAdd(base + n, R0[n] * 0.28209479177387814f);
        #pragma unroll
        for (int n = 0; n < 6; ++n) {
            #pragma unroll
            for (int m = 0; m < 3; ++m)
                atomicAdd(base + 8 + n*3 + m, R1[n] * sh1v[m]);
        }
        #pragma unroll
        for (int n = 0; n < 4; ++n) {
            #pragma unroll
            for (int m = 0; m < 5; ++m)
                atomicAdd(base + 26 + n*5 + m, R2[n] * sh2v[m]);
        }
        #pragma unroll
        for (int n = 0; n < 2; ++n) {
            #pragma unroll
            for (int m = 0; m < 7; ++m)
                atomicAdd(base + 46 + n*7 + m, R3[n] * sh3v[m]);
        }
    }
    __syncthreads();

    // ---- phase 2: mixing, channel j ----
    float Bj = 0.0f;
    {
        float a0 = 0.0f;
        #pragma unroll
        for (int i = 0; i < 32; ++i)
            a0 = fmaf(W2[i*128 + j], Tl[(i >> 3)*60 + (i & 7)], a0);
        Bj += a0 * a0;
    }
    {
        float a[3] = {0.f, 0.f, 0.f};
        #pragma unroll
        for (int i = 0; i < 24; ++i) {
            const int s = i / 6, n = i % 6;
            const float w = W2[4096 + i*128 + j];
            #pragma unroll
            for (int m = 0; m < 3; ++m)
                a[m] = fmaf(w, Tl[s*60 + 8 + n*3 + m], a[m]);
        }
        Bj += (a[0]*a[0] + a[1]*a[1] + a[2]*a[2]) * 0.57735026918962576f;
    }
    {
        float a[5] = {0.f, 0.f, 0.f, 0.f, 0.f};
        #pragma unroll
        for (int i = 0; i < 16; ++i) {
            const int s = i >> 2, n = i & 3;
            const float w = W2[7168 + i*128 + j];
            #pragma unroll
            for (int m = 0; m < 5; ++m)
                a[m] = fmaf(w, Tl[s*60 + 26 + n*5 + m], a[m]);
        }
        float ss = a[0]*a[0] + a[1]*a[1] + a[2]*a[2] + a[3]*a[3] + a[4]*a[4];
        Bj += ss * 0.44721359549995794f;
    }
    {
        float a[7] = {0.f, 0.f, 0.f, 0.f, 0.f, 0.f, 0.f};
        #pragma unroll
        for (int i = 0; i < 8; ++i) {
            const int s = i >> 1, n = i & 1;
            const float w = W2[9216 + i*128 + j];
            #pragma unroll
            for (int m = 0; m < 7; ++m)
                a[m] = fmaf(w, Tl[s*60 + 46 + n*7 + m], a[m]);
        }
        float ss = 0.0f;
        #pragma unroll
        for (int m = 0; m < 7; ++m) ss = fmaf(a[m], a[m], ss);
        Bj += ss * 0.37796447300922725f;
    }

    const int sp = species[atom];
    float B4 = Bj * Bj;
    float hidden = B4 * emb2[sp*128 + j];
    float v = hidden * w_out[j];

    #pragma unroll
    for (int o = 32; o > 0; o >>= 1) v += __shfl_down(v, o, 64);
    if ((j & 63) == 0) red[j >> 6] = v;
    __syncthreads();
    if (j == 0) {
        float tot = red[0] + red[1];
        float at  = fmaf(tot, scaling[0], comp_weights[sp]);
        atomicAdd(&out[batch_seg[atom]], at);
    }
}

extern "C" void kernel_launch(void* const* d_in, const int* in_sizes, int n_in,
                              void* d_out, int out_size, void* d_ws, size_t ws_size,
                              hipStream_t stream)
{
    const float* pos  = (const float*)d_in[0];
    const float* emb  = (const float*)d_in[1];
    const float* wr0  = (const float*)d_in[2];
    const float* wm0  = (const float*)d_in[3];
    const float* wr1  = (const float*)d_in[4];
    const float* wm1  = (const float*)d_in[5];
    const float* wr2  = (const float*)d_in[6];
    const float* wm2  = (const float*)d_in[7];
    const float* wr3  = (const float*)d_in[8];
    const float* wm3  = (const float*)d_in[9];
    const float* emb2 = (const float*)d_in[10];
    const float* wout = (const float*)d_in[11];
    const float* cw   = (const float*)d_in[12];
    const float* scal = (const float*)d_in[13];
    const int* species   = (const int*)d_in[14];
    const int* senders   = (const int*)d_in[15];
    const int* receivers = (const int*)d_in[16];
    const int* batch_seg = (const int*)d_in[17];

    int* counts  = (int*)d_ws;              // 10000 (pad to 10016)
    int* offsets = counts + 10016;          // 10001 (pad to 10016)
    int* cursor  = offsets + 10016;         // 10000 (pad to 10016)
    int* csr     = cursor + 10016;          // 200000
    float* W2    = (float*)(csr + 200000);  // 10240 floats

    hipMemsetAsync(counts, 0, 10000 * sizeof(int), stream);
    hipMemsetAsync(d_out, 0, (size_t)out_size * sizeof(float), stream);

    prep_w2_kernel<<<40, 256, 0, stream>>>(emb, wm0, wm1, wm2, wm3, W2);
    count_kernel<<<(NEDGES + 255)/256, 256, 0, stream>>>(receivers, counts);
    scan_kernel<<<1, 1024, 0, stream>>>(counts, offsets, cursor);
    scatter_kernel<<<(NEDGES + 255)/256, 256, 0, stream>>>(receivers, cursor, csr);
    fused_atom_kernel<<<NATOMS, 128, 0, stream>>>(
        pos, wr0, wr1, wr2, wr3, species, senders, offsets, csr,
        W2, emb2, wout, cw, scal, batch_seg, (float*)d_out);
}